// Round 5
// baseline (82.288 us; speedup 1.0000x reference)
//
#include <hip/hip_runtime.h>
#include <hip/hip_bf16.h>

#define BB 64
#define TT 256
#define HH 200
#define KK 48

typedef __attribute__((ext_vector_type(8))) short bf16x8;
typedef __attribute__((ext_vector_type(4))) float f32x4;

// ws layout (bf16 elements): [0, 3276800) feats_bf (16384 x 200), then W_bf (48 x 200)
#define NFEAT (BB * TT * HH)       // 3,276,800
#define NW    (KK * HH)            // 9,600
#define NF8   (NFEAT / 8)          // 409,600 groups of 8
#define NW8   (NW / 8)             // 1,200 groups of 8

static __device__ __forceinline__ unsigned short f2bf(float x) {
    __hip_bfloat16 h = __float2bfloat16(x);
    return *reinterpret_cast<unsigned short*>(&h);
}

__global__ __launch_bounds__(256)
void cvt_kernel(const float* __restrict__ feats, const float* __restrict__ W_e,
                unsigned short* __restrict__ bf, float* __restrict__ out)
{
    const int i = blockIdx.x * 256 + threadIdx.x;   // one 8-elem group
    const float4* src4 = nullptr;
    unsigned short* dst = nullptr;
    if (i < NF8) {
        src4 = reinterpret_cast<const float4*>(feats) + (size_t)i * 2;
        dst  = bf + (size_t)i * 8;
    } else if (i < NF8 + NW8) {
        const int j = i - NF8;
        src4 = reinterpret_cast<const float4*>(W_e) + (size_t)j * 2;
        dst  = bf + (size_t)NFEAT + (size_t)j * 8;
    }
    if (src4) {
        const float4 v0 = src4[0];
        const float4 v1 = src4[1];
        bf16x8 o;
        o[0] = (short)f2bf(v0.x); o[1] = (short)f2bf(v0.y);
        o[2] = (short)f2bf(v0.z); o[3] = (short)f2bf(v0.w);
        o[4] = (short)f2bf(v1.x); o[5] = (short)f2bf(v1.y);
        o[6] = (short)f2bf(v1.z); o[7] = (short)f2bf(v1.w);
        *reinterpret_cast<bf16x8*>(dst) = o;
    }
    if (blockIdx.x == 0 && threadIdx.x < BB) out[threadIdx.x] = 0.0f;  // zero accumulators
}

// 1024 blocks x 192 threads. Block = (batch b, 16-t slice); wave w = k-quarter.
// Swapped GEMM: D = W . feats^T  ->  lane holds em[k = w*16+rg*4+j][t = t0+cc].
__global__ __launch_bounds__(192)
void crf_main(const unsigned short* __restrict__ bfws,
              const float* __restrict__ b_e,
              const int*   __restrict__ targets,
              const int*   __restrict__ mask,
              const int*   __restrict__ end_tag_p,
              float*       __restrict__ out)
{
    __shared__ float Lm[3][16], Ls[3][16], Lg[3][16], Le[3][16];

    const int tid  = threadIdx.x;
    const int lane = tid & 63;
    const int w    = tid >> 6;          // k-quarter 0..2
    const int bidx = blockIdx.x >> 4;   // batch
    const int sq   = blockIdx.x & 15;   // 16-t slice
    const int t0   = sq * 16;

    // ---- mask length (wave-redundant; 64 lanes x int4 = 256 ints) ----
    int len;
    {
        const int4 mv4 = reinterpret_cast<const int4*>(mask + bidx * TT)[lane];
        int mv = mv4.x + mv4.y + mv4.z + mv4.w;
        #pragma unroll
        for (int off = 32; off >= 1; off >>= 1) mv += __shfl_xor(mv, off);
        len = mv;
    }

    const int rg = lane >> 4;   // 0..3
    const int cc = lane & 15;   // t within slice / A-row within quarter

    // A = W rows [w*16, w*16+16); B = feats^T cols = t rows of feats
    const unsigned short* Wb = bfws + (size_t)NFEAT + (size_t)(w * 16 + cc) * HH;
    const unsigned short* Fb = bfws + (size_t)(bidx * TT + t0 + cc) * HH;

    f32x4 acc = {0.f, 0.f, 0.f, 0.f};
    #pragma unroll
    for (int kc = 0; kc < 7; ++kc) {
        bf16x8 a, b;
        if (kc < 6 || rg == 0) {          // h = kc*32 + rg*8; valid iff < 200
            a = *reinterpret_cast<const bf16x8*>(Wb + kc * 32 + rg * 8);
            b = *reinterpret_cast<const bf16x8*>(Fb + kc * 32 + rg * 8);
        } else {
            a = (bf16x8)(short)0; b = a;
        }
        acc = __builtin_amdgcn_mfma_f32_16x16x32_bf16(a, b, acc, 0, 0, 0);
    }

    // ---- epilogue: lane holds em[k = w*16+rg*4+j][t = t0+cc] ----
    const float4 b4 = *reinterpret_cast<const float4*>(b_e + w * 16 + rg * 4);
    const float x0 = acc[0] + b4.x, x1 = acc[1] + b4.y;
    const float x2 = acc[2] + b4.z, x3 = acc[3] + b4.w;

    const int ET  = end_tag_p[0];
    const int tgt = targets[bidx * TT + t0 + cc] % KK;
    const int kb  = w * 16 + rg * 4;

    float m = fmaxf(fmaxf(x0, x1), fmaxf(x2, x3));
    m = fmaxf(m, __shfl_xor(m, 16));
    m = fmaxf(m, __shfl_xor(m, 32));           // max over quarter's 16 k's (per t)
    float s = expf(x0 - m) + expf(x1 - m) + expf(x2 - m) + expf(x3 - m);
    float g = ((kb     == tgt) ? x0 : 0.f) + ((kb + 1 == tgt) ? x1 : 0.f)
            + ((kb + 2 == tgt) ? x2 : 0.f) + ((kb + 3 == tgt) ? x3 : 0.f);
    float e = ((kb     == ET) ? x0 : 0.f) + ((kb + 1 == ET) ? x1 : 0.f)
            + ((kb + 2 == ET) ? x2 : 0.f) + ((kb + 3 == ET) ? x3 : 0.f);
    s += __shfl_xor(s, 16); s += __shfl_xor(s, 32);
    g += __shfl_xor(g, 16); g += __shfl_xor(g, 32);
    e += __shfl_xor(e, 16); e += __shfl_xor(e, 32);

    if (rg == 0) { Lm[w][cc] = m; Ls[w][cc] = s; Lg[w][cc] = g; Le[w][cc] = e; }
    __syncthreads();

    // ---- combine 3 quarters per t, form contribution, reduce 16 t ----
    if (tid < 16) {
        const float m0 = Lm[0][tid], m1 = Lm[1][tid], m2 = Lm[2][tid];
        const float M  = fmaxf(fmaxf(m0, m1), m2);
        const float S  = Ls[0][tid] * expf(m0 - M)
                       + Ls[1][tid] * expf(m1 - M)
                       + Ls[2][tid] * expf(m2 - M);
        const float lse  = M + logf(S);
        const float gold = Lg[0][tid] + Lg[1][tid] + Lg[2][tid];
        const float eend = Le[0][tid] + Le[1][tid] + Le[2][tid];
        const int gt = t0 + tid;

        float c = 0.0f;
        if (gt < len)          c -= gold;
        if (gt == len - 1)     c += eend;
        else if (gt < len - 1) c += lse;

        #pragma unroll
        for (int off = 8; off >= 1; off >>= 1) c += __shfl_xor(c, off);
        if (tid == 0) atomicAdd(out + bidx, c);
    }
}

extern "C" void kernel_launch(void* const* d_in, const int* in_sizes, int n_in,
                              void* d_out, int out_size, void* d_ws, size_t ws_size,
                              hipStream_t stream) {
    const float* feats   = (const float*)d_in[0];
    const float* W_e     = (const float*)d_in[1];
    const float* b_e     = (const float*)d_in[2];
    const int*   targets = (const int*)d_in[3];
    const int*   mask    = (const int*)d_in[4];
    const int*   et      = (const int*)d_in[6];
    float*       out     = (float*)d_out;
    unsigned short* bfws = (unsigned short*)d_ws;

    const int cvt_grid = (NF8 + NW8 + 255) / 256;   // 1606
    cvt_kernel<<<dim3(cvt_grid), dim3(256), 0, stream>>>(feats, W_e, bfws, out);
    crf_main<<<dim3(BB * 16), dim3(192), 0, stream>>>(bfws, b_e, targets, mask, et, out);
}